// Round 4
// baseline (599.823 us; speedup 1.0000x reference)
//
#include <hip/hip_runtime.h>
#include <hip/hip_bf16.h>
#include <stdint.h>

#define BB 2
#define SS 2048
#define DD 1024
#define HH 8
#define HD 128
#define TOPK 32
#define ROWS (BB*HH*SS)   // 32768
#define SPLITK 4

typedef float f32x4 __attribute__((ext_vector_type(4)));
typedef _Float16 f16x8 __attribute__((ext_vector_type(8)));
typedef _Float16 f16x4 __attribute__((ext_vector_type(4)));

// ---------------------------------------------------------------- K1: top-32
// Fixed-threshold compaction + parallel rank selection. Composite u64 key
// (sortable_value<<11 | (2047-idx)) == exact stable-argsort tie semantics.
__global__ __launch_bounds__(256) void topk_kernel(const float* __restrict__ aw,
                                                   int* __restrict__ idx_out) {
    const int row = blockIdx.x;
    const float* p = aw + (size_t)row * SS;
    const int t = threadIdx.x;
    float4 v0 = *(const float4*)(p + 4 * t);
    float4 v1 = *(const float4*)(p + 1024 + 4 * t);
    float vals[8] = {v0.x, v0.y, v0.z, v0.w, v1.x, v1.y, v1.z, v1.w};
    unsigned long long key[8];
#pragma unroll
    for (int i = 0; i < 8; i++) {
        int e = (i < 4) ? (4 * t + i) : (1024 + 4 * t + (i - 4));
        unsigned u = __float_as_uint(vals[i]);
        unsigned sk = (u & 0x80000000u) ? ~u : (u | 0x80000000u);
        key[i] = ((unsigned long long)sk << 11) | (unsigned)(2047 - e);
    }
    __shared__ int s_cnt;
    __shared__ int s_red[4];
    __shared__ unsigned long long s_cand[256];
    const int lane = t & 63, wv = t >> 6;

    // N(0,1) quantile ~1.76 -> E[survivors] ~ 80: essentially always in [32,256]
    unsigned thr0 = __float_as_uint(1.76f) | 0x80000000u;
    unsigned long long T = ((unsigned long long)thr0 << 11) | 2047ull;

    if (t == 0) s_cnt = 0;
    __syncthreads();
#pragma unroll
    for (int i = 0; i < 8; i++) {
        if (key[i] > T) {
            int pos = atomicAdd(&s_cnt, 1);
            if (pos < 256) s_cand[pos] = key[i];
        }
    }
    __syncthreads();

    if (s_cnt < TOPK || s_cnt > 256) {
        // rare fallback: bisect threshold until count in range, recompact
        unsigned long long lo = 0, hi = ~0ull;
        if (s_cnt > 256) lo = T; else hi = T;
        T = lo + ((hi - lo) >> 1);
        for (int it = 0; it < 40; ++it) {
            int c = 0;
#pragma unroll
            for (int i = 0; i < 8; i++) c += (key[i] > T) ? 1 : 0;
            for (int off = 32; off; off >>= 1) c += __shfl_down(c, off, 64);
            if (lane == 0) s_red[wv] = c;
            __syncthreads();
            int tot = s_red[0] + s_red[1] + s_red[2] + s_red[3];
            if (tot >= TOPK && tot <= 256) break;
            if (tot > 256) lo = T; else hi = T;
            T = lo + ((hi - lo) >> 1);
            __syncthreads();
        }
        if (t == 0) s_cnt = 0;
        __syncthreads();
#pragma unroll
        for (int i = 0; i < 8; i++) {
            if (key[i] > T) {
                int pos = atomicAdd(&s_cnt, 1);
                if (pos < 256) s_cand[pos] = key[i];
            }
        }
        __syncthreads();
    }

    const int C = s_cnt < 256 ? s_cnt : 256;
    if (t < C) {
        unsigned long long mk = s_cand[t];
        int rank = 0;
        for (int j = 0; j < C; ++j)
            rank += (s_cand[j] > mk) ? 1 : 0;   // broadcast LDS read
        if (rank < TOPK)
            idx_out[(size_t)row * TOPK + rank] = 2047 - (int)(mk & 2047ull);
    }
}

// ------------------------------------------------ K1b: convert k -> fp16 head-major
// kh[bh][s][128]: removes per-tile fp32->fp16 cvt from stats staging (was done
// 32x redundantly) and halves staging load bytes.
__global__ __launch_bounds__(256) void convk_kernel(const float* __restrict__ k,
                                                    _Float16* __restrict__ kh) {
    const int f = blockIdx.x * 256 + threadIdx.x;   // float4 index, 0..1048575
    const int row = f >> 8;                         // b*SS + s
    const int c4 = f & 255;
    const int h = c4 >> 5, d4 = c4 & 31;
    const int b = row >> 11, s = row & 2047;
    float4 kv = ((const float4*)k)[f];
    f16x4 o = {(_Float16)kv.x, (_Float16)kv.y, (_Float16)kv.z, (_Float16)kv.w};
    *(f16x4*)&kh[(((size_t)(b * HH + h) * SS + s) * HD) + d4 * 4] = o;
}

// ------------------------------------------------------- K2: softmax stats
// fp16 MFMA (not bf16): eps*Z dominates the renorm denominator, so Z's
// relative error is a per-(head,row) output scale that LN does NOT cancel.
// Q fragments held in registers (loop-invariant); only K staged in LDS.
// Split-K=4 -> 1024 blocks; LDS 34.8KB -> better occupancy.
#define KPAD 136   // 128 + 8 halves pad; ds_write/read land 2-way max (free)

__global__ __launch_bounds__(256) void stats_kernel(const float* __restrict__ q,
                                                    const _Float16* __restrict__ kh,
                                                    float* __restrict__ ws_m,
                                                    float* __restrict__ ws_l) {
    __shared__ __align__(16) _Float16 Ks[128 * KPAD];
    const int bh = blockIdx.x & 15;          // XCD swizzle: blockIdx%8 = bh%8
    const int qt = (blockIdx.x >> 4) & 15;
    const int quarter = blockIdx.x >> 8;     // 0..3
    const int b = bh >> 3, h = bh & 7;
    const int t = threadIdx.x;
    const int wv = t >> 6, lane = t & 63;
    const int l16 = lane & 15, quad = lane >> 4;

    // Q fragments straight from fp32 global into registers (once per block)
    const float* qb = q + ((size_t)(b * SS + qt * 128)) * DD + h * HD;
    f16x8 qfrag[2][4];
#pragma unroll
    for (int a = 0; a < 2; a++)
#pragma unroll
        for (int ks = 0; ks < 4; ks++) {
            const float* src = qb + (size_t)(wv * 32 + a * 16 + l16) * DD + ks * 32 + quad * 8;
            float4 x0 = *(const float4*)src;
            float4 x1 = *(const float4*)(src + 4);
            qfrag[a][ks] = (f16x8){(_Float16)x0.x, (_Float16)x0.y, (_Float16)x0.z, (_Float16)x0.w,
                                   (_Float16)x1.x, (_Float16)x1.y, (_Float16)x1.z, (_Float16)x1.w};
        }

    float mrun[2][4], lrun[2][4];
#pragma unroll
    for (int a = 0; a < 2; a++)
#pragma unroll
        for (int r2 = 0; r2 < 4; r2++) { mrun[a][r2] = -INFINITY; lrun[a][r2] = 0.f; }

    const _Float16* khb = kh + (size_t)bh * SS * HD;
    for (int kt = quarter * 4; kt < quarter * 4 + 4; ++kt) {
        __syncthreads();
#pragma unroll
        for (int j = 0; j < 8; ++j) {   // stage 128x128 fp16 tile: 8x16B per thread
            int c = t + 256 * j;
            int r = c >> 4, c16 = c & 15;
            f16x8 val = *(const f16x8*)&khb[(size_t)(kt * 128 + r) * HD + c16 * 8];
            *(f16x8*)&Ks[r * KPAD + c16 * 8] = val;
        }
        __syncthreads();
        f32x4 acc[2][8];
#pragma unroll
        for (int a = 0; a < 2; a++)
#pragma unroll
            for (int n = 0; n < 8; n++) acc[a][n] = (f32x4){0.f, 0.f, 0.f, 0.f};
#pragma unroll
        for (int ks = 0; ks < 4; ++ks) {
            f16x8 bfr[8];
#pragma unroll
            for (int n = 0; n < 8; n++)
                bfr[n] = *(const f16x8*)&Ks[(n * 16 + l16) * KPAD + ks * 32 + quad * 8];
#pragma unroll
            for (int a = 0; a < 2; a++)
#pragma unroll
                for (int n = 0; n < 8; n++)
                    acc[a][n] = __builtin_amdgcn_mfma_f32_16x16x32_f16(qfrag[a][ks], bfr[n], acc[a][n], 0, 0, 0);
        }
        // online max / sumexp per row (row = wv*32 + a*16 + quad*4 + r2)
#pragma unroll
        for (int a = 0; a < 2; a++) {
#pragma unroll
            for (int r2 = 0; r2 < 4; r2++) {
                float tm = acc[a][0][r2];
#pragma unroll
                for (int n = 1; n < 8; n++) tm = fmaxf(tm, acc[a][n][r2]);
#pragma unroll
                for (int off = 1; off < 16; off <<= 1) tm = fmaxf(tm, __shfl_xor(tm, off, 64));
                float tl = 0.f;
#pragma unroll
                for (int n = 0; n < 8; n++) tl += __expf(acc[a][n][r2] - tm);
#pragma unroll
                for (int off = 1; off < 16; off <<= 1) tl += __shfl_xor(tl, off, 64);
                float mo = mrun[a][r2];
                float mn = fmaxf(mo, tm);
                lrun[a][r2] = lrun[a][r2] * __expf(mo - mn) + tl * __expf(tm - mn);
                mrun[a][r2] = mn;
            }
        }
    }
    if (l16 == 0) {
#pragma unroll
        for (int a = 0; a < 2; a++)
#pragma unroll
            for (int r2 = 0; r2 < 4; r2++) {
                int rrow = qt * 128 + wv * 32 + a * 16 + quad * 4 + r2;
                size_t g = (size_t)quarter * ROWS + (size_t)bh * SS + rrow;
                ws_m[g] = mrun[a][r2];
                ws_l[g] = lrun[a][r2];
            }
    }
}

// --------------------------------------------- K2b: gather scores + PV (fp32)
// One 64-lane wave per q-row: zero LDS, zero barriers. idx/weights shared via
// shfl. XCD swizzle: bh = blockIdx&15 -> each XCD's L2 holds its 2 heads' k+v.
__global__ __launch_bounds__(256) void attnout_kernel(const float* __restrict__ q,
                                                      const float* __restrict__ k,
                                                      const float* __restrict__ v,
                                                      const int* __restrict__ idx_ws,
                                                      const float* __restrict__ ws_m,
                                                      const float* __restrict__ ws_l,
                                                      float* __restrict__ out) {
    const int bh = blockIdx.x & 15;
    const int sg = blockIdx.x >> 4;          // 0..511
    const int wv = threadIdx.x >> 6, lane = threadIdx.x & 63;
    const int s = sg * 4 + wv;
    const int b = bh >> 3, h = bh & 7;
    const int R = (bh << 11) | s;

    int idxr = idx_ws[(size_t)R * TOPK + (lane & 31)];   // lane l holds idx[l&31]

    // merge split-K partial stats (broadcast loads: all lanes same address)
    float mp0 = ws_m[R], mp1 = ws_m[(size_t)ROWS + R];
    float mp2 = ws_m[2 * (size_t)ROWS + R], mp3 = ws_m[3 * (size_t)ROWS + R];
    float m = fmaxf(fmaxf(mp0, mp1), fmaxf(mp2, mp3));
    float Z = ws_l[R] * __expf(mp0 - m) + ws_l[(size_t)ROWS + R] * __expf(mp1 - m)
            + ws_l[2 * (size_t)ROWS + R] * __expf(mp2 - m)
            + ws_l[3 * (size_t)ROWS + R] * __expf(mp3 - m);

    // exact fp32 dots: 2 lanes per selected key, 64 floats each
    const int sel = lane >> 1, half = lane & 1;
    const int ki = __shfl(idxr, sel);
    const float4* qr = (const float4*)(q + ((size_t)(b * SS) + s) * DD + h * HD + half * 64);
    const float4* kr = (const float4*)(k + ((size_t)(b * SS) + ki) * DD + h * HD + half * 64);
    float d = 0.f;
#pragma unroll
    for (int c = 0; c < 16; ++c) {
        float4 a = qr[c], kk = kr[c];
        d += a.x * kk.x + a.y * kk.y + a.z * kk.z + a.w * kk.w;
    }
    d += __shfl_xor(d, 1);
    float e = __shfl(__expf(d - m), 2 * (lane & 31));   // lane l -> e_{l&31}
    float Ssum = e;
#pragma unroll
    for (int off = 1; off < 32; off <<= 1) Ssum += __shfl_xor(Ssum, off); // within 32-halves
    float w = e / (Ssum + 1e-5f * Z);                   // S_sel + eps*Z (exact renorm)

    // PV: lane covers dims 2*lane, 2*lane+1 (float2 loads)
    const float* vbh = v + (size_t)b * SS * DD + h * HD;
    float a0 = 0.f, a1 = 0.f;
#pragma unroll
    for (int i = 0; i < TOPK; ++i) {
        int vi = __shfl(idxr, i);
        float wi = __shfl(w, i);
        float2 vv = *(const float2*)(vbh + (size_t)vi * DD + 2 * lane);
        a0 += wi * vv.x;
        a1 += wi * vv.y;
    }
    float* orow = out + ((size_t)(b * SS) + s) * DD + h * HD;
    ((float2*)orow)[lane] = make_float2(a0, a1);
}

// ----------------------------------------------------- K3: LayerNorm in-place
__global__ __launch_bounds__(256) void ln_kernel(float* __restrict__ out,
                                                 const float* __restrict__ gamma,
                                                 const float* __restrict__ beta) {
    const int row = blockIdx.x;   // B*S = 4096
    float* p = out + (size_t)row * DD;
    const int t = threadIdx.x;
    float x[4];
#pragma unroll
    for (int i = 0; i < 4; i++) x[i] = p[t + 256 * i];
    float sum = x[0] + x[1] + x[2] + x[3];
    __shared__ float red[4];
    const int lane = t & 63, wv = t >> 6;
    for (int off = 32; off; off >>= 1) sum += __shfl_down(sum, off, 64);
    if (lane == 0) red[wv] = sum;
    __syncthreads();
    float mean = (red[0] + red[1] + red[2] + red[3]) * (1.f / DD);
    __syncthreads();
    float vs = 0.f;
#pragma unroll
    for (int i = 0; i < 4; i++) { float dd = x[i] - mean; vs += dd * dd; }
    for (int off = 32; off; off >>= 1) vs += __shfl_down(vs, off, 64);
    if (lane == 0) red[wv] = vs;
    __syncthreads();
    float var = (red[0] + red[1] + red[2] + red[3]) * (1.f / DD);
    float inv = rsqrtf(var + 1e-5f);
#pragma unroll
    for (int i = 0; i < 4; i++) {
        int c = t + 256 * i;
        p[c] = (x[i] - mean) * inv * gamma[c] + beta[c];
    }
}

extern "C" void kernel_launch(void* const* d_in, const int* in_sizes, int n_in,
                              void* d_out, int out_size, void* d_ws, size_t ws_size,
                              hipStream_t stream) {
    const float* q = (const float*)d_in[0];
    const float* k = (const float*)d_in[1];
    const float* v = (const float*)d_in[2];
    const float* aw = (const float*)d_in[3];
    const float* gamma = (const float*)d_in[4];
    const float* beta = (const float*)d_in[5];
    float* out = (float*)d_out;

    char* wp = (char*)d_ws;
    int* idx_ws = (int*)wp;                    wp += (size_t)ROWS * TOPK * sizeof(int);
    float* ws_m = (float*)wp;                  wp += (size_t)SPLITK * ROWS * sizeof(float);
    float* ws_l = (float*)wp;                  wp += (size_t)SPLITK * ROWS * sizeof(float);
    _Float16* kh = (_Float16*)wp;              // 16*2048*128 fp16 = 8 MB

    hipLaunchKernelGGL(topk_kernel, dim3(ROWS), dim3(256), 0, stream, aw, idx_ws);
    hipLaunchKernelGGL(convk_kernel, dim3(4096), dim3(256), 0, stream, k, kh);
    hipLaunchKernelGGL(stats_kernel, dim3(256 * SPLITK), dim3(256), 0, stream, q, kh, ws_m, ws_l);
    hipLaunchKernelGGL(attnout_kernel, dim3(8192), dim3(256), 0, stream, q, k, v, idx_ws, ws_m, ws_l, out);
    hipLaunchKernelGGL(ln_kernel, dim3(BB * SS), dim3(256), 0, stream, out, gamma, beta);
}